// Round 5
// baseline (31.694 us; speedup 1.0000x reference)
//
#include <hip/hip_runtime.h>

// IntervalTimeEncoder:
//   diff = ts[:,1:] - ts[:,:-1]                       [B, L]
//   idx  = clamp(floor(diff / PER_TIME), 0, 511)       (relu + JAX gather-clamp)
//   out0 = W[idx] + b                                  [B, L, 64] f32
//   out1 = ts[:, :-1]                                  [B, L]     f32
// d_in: [0]=input (int32, UNUSED), [1]=timestamp f32 [B, L+1], [2]=W f32 [512,64], [3]=b f32 [64]
// d_out: out0 (B*L*64 floats) then out1 (B*L floats), concatenated flat.
//
// History: R1=28.9us (direct map), R3=44.6us (NT stores — L2 bypass kills the
// write stream), R4=29.1us (batched, plain stores — neutral => not latency/
// dispatch bound). Theory R5: the per-output W gather doubles L2-side traffic
// (134MB rd + 136MB wr = 9.3 TB/s mixed, while write-only fills do 6.7 TB/s)
// -> reads and writes share an L2/TA port budget. Fix: W (128KB) fully
// resident in LDS (static __shared__, gfx950 has 160KB/CU), 1 block/CU,
// hot loop becomes ds_read gather + pure store stream.

#define B_DIM 64
#define L_DIM 8192
#define TIME_DIM 64
#define N_TI 512

#define GRID 256
#define BLOCK 1024
#define ROWS_TOTAL (B_DIM * L_DIM)              // 524288
#define ROWS_PER_BLOCK (ROWS_TOTAL / GRID)      // 2048
#define ROWS_PER_ITER (BLOCK / 16)              // 64 rows per block-iteration
#define NITER (ROWS_PER_BLOCK / ROWS_PER_ITER)  // 32

typedef float f32x4 __attribute__((ext_vector_type(4)));

__global__ __launch_bounds__(BLOCK) void IntervalTimeEncoder_77653008712021_kernel(
    const float* __restrict__ ts,     // [B, L+1]
    const float* __restrict__ W,      // [512, 64]
    const float* __restrict__ bias,   // [64]
    float* __restrict__ emb,          // [B, L, 64]
    float* __restrict__ ts_out)       // [B, L]
{
    // 512 rows x 16 f32x4 = 8192 x 16B = 128 KB (fits gfx950 160KB LDS)
    __shared__ f32x4 Wlds[N_TI * (TIME_DIM / 4)];

    const f32x4* __restrict__ W4 = reinterpret_cast<const f32x4*>(W);
    // cooperative stage: 8 x f32x4 per thread, coalesced
    #pragma unroll
    for (int i = 0; i < N_TI * (TIME_DIM / 4) / BLOCK; ++i) {
        const int e = i * BLOCK + threadIdx.x;
        Wlds[e] = W4[e];
    }

    const int d4  = threadIdx.x & 15;          // which float4 of the 64-dim row
    const int rl0 = threadIdx.x >> 4;          // 0..63, local row within iter
    const int rowBase = blockIdx.x * ROWS_PER_BLOCK;
    const f32x4 bb = reinterpret_cast<const f32x4*>(bias)[d4];
    f32x4* __restrict__ emb4 = reinterpret_cast<f32x4*>(emb);

    __syncthreads();

    #pragma unroll
    for (int it = 0; it < NITER; it += 4) {
        int   rows[4];
        float t0[4], t1[4];

        // Phase 1: issue all ts loads (independent)
        #pragma unroll
        for (int j = 0; j < 4; ++j) {
            const int row  = rowBase + (it + j) * ROWS_PER_ITER + rl0;
            const int b    = row >> 13;            // / L_DIM
            const int l    = row & (L_DIM - 1);
            const int base = b * (L_DIM + 1) + l;
            rows[j] = row;
            t0[j] = ts[base];
            t1[j] = ts[base + 1];
        }

        // Phase 2: indices + LDS gathers
        f32x4 w[4];
        #pragma unroll
        for (int j = 0; j < 4; ++j) {
            const float diff = t1[j] - t0[j];
            // bit-match jnp: true f32 divide, floor, relu, JAX gather-clamp
            int idx = (int)floorf(diff / 1953.125f);
            idx = idx < 0 ? 0 : idx;
            idx = idx > (N_TI - 1) ? (N_TI - 1) : idx;
            w[j] = Wlds[idx * (TIME_DIM / 4) + d4];
        }

        // Phase 3: bias-add + pure coalesced store stream
        #pragma unroll
        for (int j = 0; j < 4; ++j) {
            emb4[(size_t)rows[j] * (TIME_DIM / 4) + d4] = w[j] + bb;
            if (d4 == 0) {
                ts_out[rows[j]] = t0[j];
            }
        }
    }
}

extern "C" void kernel_launch(void* const* d_in, const int* in_sizes, int n_in,
                              void* d_out, int out_size, void* d_ws, size_t ws_size,
                              hipStream_t stream) {
    (void)in_sizes; (void)n_in; (void)d_ws; (void)ws_size; (void)out_size;
    // d_in[0] = input (int32) — unused by the reference outputs
    const float* ts   = (const float*)d_in[1];
    const float* W    = (const float*)d_in[2];
    const float* bias = (const float*)d_in[3];

    float* emb    = (float*)d_out;                                     // [B, L, 64]
    float* ts_out = (float*)d_out + (size_t)B_DIM * L_DIM * TIME_DIM;  // [B, L]

    IntervalTimeEncoder_77653008712021_kernel<<<GRID, BLOCK, 0, stream>>>(
        ts, W, bias, emb, ts_out);
}

// Round 6
// 28.624 us; speedup vs baseline: 1.1073x; 1.1073x over previous
//
#include <hip/hip_runtime.h>

// IntervalTimeEncoder:
//   diff = ts[:,1:] - ts[:,:-1]                       [B, L]
//   idx  = clamp(floor(diff / PER_TIME), 0, 511)       (relu + JAX gather-clamp)
//   out0 = W[idx] + b                                  [B, L, 64] f32
//   out1 = ts[:, :-1]                                  [B, L]     f32
// d_in: [0]=input (int32, UNUSED), [1]=timestamp f32 [B, L+1], [2]=W f32 [512,64], [3]=b f32 [64]
// d_out: out0 (B*L*64 floats) then out1 (B*L floats), concatenated flat.
//
// History: R1=28.9 (direct map, predicated ts_out scatter), R3=44.6 (NT stores
// — L2 bypass kills write stream), R4=29.1 (batched — neutral => not
// latency/dispatch bound), R5=31.7 (W in LDS — neutral => not L2-read bound).
// Theory R6: the last fill-vs-us structural diff is the predicated d4==0
// ts_out scatter woven into the write stream (partial-wave 4B stores at 256B
// stride + exec-mask churn every 4th store). Split by block: emb blocks do a
// pure fill-like stream; 512 dedicated tail blocks do ts_out with full-wave
// coalesced f32x4 stores. If this lands >=28us -> practical roofline.

#define B_DIM 64
#define L_DIM 8192
#define TIME_DIM 64
#define N_TI 512

#define BLOCK 256
#define EMB_BLOCKS (B_DIM * L_DIM * (TIME_DIM / 4) / BLOCK)  // 32768
#define TS_BLOCKS 512                                        // 512*256*4 = 524288 dwords
#define GRID (EMB_BLOCKS + TS_BLOCKS)

typedef float f32x4 __attribute__((ext_vector_type(4)));

__global__ __launch_bounds__(BLOCK) void IntervalTimeEncoder_77653008712021_kernel(
    const float* __restrict__ ts,     // [B, L+1]
    const float* __restrict__ W,      // [512, 64]
    const float* __restrict__ bias,   // [64]
    float* __restrict__ emb,          // [B, L, 64]
    float* __restrict__ ts_out)       // [B, L]
{
    if (blockIdx.x < EMB_BLOCKS) {
        // ---- pure embedding stream: 1 f32x4 per thread, no divergence ----
        const int tid = blockIdx.x * BLOCK + threadIdx.x;   // 0 .. B*L*16-1
        const int row = tid >> 4;          // flat (b, l)
        const int d4  = tid & 15;
        const int b   = row >> 13;         // / L_DIM
        const int l   = row & (L_DIM - 1);

        const int base = b * (L_DIM + 1) + l;
        const float t0 = ts[base];
        const float t1 = ts[base + 1];

        // bit-match jnp: f32 subtract, true f32 divide, floor, relu, gather-clamp
        const float diff = t1 - t0;
        int idx = (int)floorf(diff / 1953.125f);
        idx = idx < 0 ? 0 : idx;
        idx = idx > (N_TI - 1) ? (N_TI - 1) : idx;

        const f32x4 w  = reinterpret_cast<const f32x4*>(W)[idx * (TIME_DIM / 4) + d4];
        const f32x4 bb = reinterpret_cast<const f32x4*>(bias)[d4];
        reinterpret_cast<f32x4*>(emb)[row * (TIME_DIM / 4) + d4] = w + bb;
    } else {
        // ---- ts_out copy: full-wave coalesced, 4 dwords/thread, x4 store ----
        const int t    = (blockIdx.x - EMB_BLOCKS) * BLOCK + threadIdx.x;
        const int row0 = t * 4;                    // first of 4 consecutive flat rows
        const int b    = row0 >> 13;               // 4 rows never cross a b-boundary
        const int l0   = row0 & (L_DIM - 1);       // multiple of 4
        const int src  = b * (L_DIM + 1) + l0;     // may be 4B-aligned only

        f32x4 v;
        v.x = ts[src];
        v.y = ts[src + 1];
        v.z = ts[src + 2];
        v.w = ts[src + 3];
        // dst: b*L + l0, l0 % 4 == 0 -> 16B aligned
        reinterpret_cast<f32x4*>(ts_out)[row0 >> 2] = v;
    }
}

extern "C" void kernel_launch(void* const* d_in, const int* in_sizes, int n_in,
                              void* d_out, int out_size, void* d_ws, size_t ws_size,
                              hipStream_t stream) {
    (void)in_sizes; (void)n_in; (void)d_ws; (void)ws_size; (void)out_size;
    // d_in[0] = input (int32) — unused by the reference outputs
    const float* ts   = (const float*)d_in[1];
    const float* W    = (const float*)d_in[2];
    const float* bias = (const float*)d_in[3];

    float* emb    = (float*)d_out;                                     // [B, L, 64]
    float* ts_out = (float*)d_out + (size_t)B_DIM * L_DIM * TIME_DIM;  // [B, L]

    IntervalTimeEncoder_77653008712021_kernel<<<GRID, BLOCK, 0, stream>>>(
        ts, W, bias, emb, ts_out);
}